// Round 4
// baseline (355.958 us; speedup 1.0000x reference)
//
#include <hip/hip_runtime.h>

#define S_VOX (128*128*128)   // voxels per (b,n) plane
#define QV (S_VOX/4)          // float4 groups per plane = 524288
#define EPSF 1e-10f
#define SMOOTHF 1e-5f
#define NACC 49               // [0]=ce(log2), [1..16]=inter, [17..32]=ground, [33..48]=pred_o
#define LN2F 0.6931471805599453f

#define NBLK 1024             // 64 chunks per plane x 16 planes
#define CHUNK_F4 8192         // float4 groups per block (128 KB pred)
#define STAGE_F4 1024         // float4 groups per stage (16 KB LDS)
#define NSTAGES (CHUNK_F4 / STAGE_F4)   // 8

// ------------------------------------------------------------------
// Kernel A: pack both batches' 3-bit targets per voxel-quad into one u32.
// bits [6c..6c+2]=t0.c, [6c+3..6c+5]=t1.c. Block 0 also zeroes ws.
// ------------------------------------------------------------------
__global__ __launch_bounds__(256) void pack_targets(const int* __restrict__ tgt,
                                                    unsigned int* __restrict__ packed,
                                                    float* __restrict__ ws) {
    if (blockIdx.x == 0 && threadIdx.x <= NACC) ws[threadIdx.x] = 0.f;
    const int4* t4 = (const int4*)tgt;
    int q = blockIdx.x * 1024 + threadIdx.x;
#pragma unroll
    for (int i = 0; i < 4; i++, q += 256) {
        const int4 t0 = t4[q];
        const int4 t1 = t4[QV + q];
        unsigned int m = (unsigned)(t0.x & 7)        | ((unsigned)(t1.x & 7) << 3)
                       | ((unsigned)(t0.y & 7) << 6) | ((unsigned)(t1.y & 7) << 9)
                       | ((unsigned)(t0.z & 7) << 12)| ((unsigned)(t1.z & 7) << 15)
                       | ((unsigned)(t0.w & 7) << 18)| ((unsigned)(t1.w & 7) << 21);
        packed[q] = m;
    }
}

// ------------------------------------------------------------------
// Kernel B: plane-chunked streaming with async global->LDS double buffer.
// ------------------------------------------------------------------
__global__ __launch_bounds__(256) void dice_main(const float* __restrict__ pred,
                                                 const unsigned int* __restrict__ packed,
                                                 float* __restrict__ ws,
                                                 float* __restrict__ out) {
    const int plane = blockIdx.x & 15;        // b = plane>>3, n = plane&7
    const int chunk = blockIdx.x >> 4;        // [0,64)
    const int b     = plane >> 3;
    const int n     = plane & 7;

    const float4* p4 = (const float4*)pred + (size_t)plane * QV;
    const int base0 = chunk * CHUNK_F4;       // plane-local f4 index of this block

    __shared__ float4 sbuf[2][STAGE_F4];      // 2 x 16 KB
    __shared__ float  red[4][4];

    const int tid  = threadIdx.x;
    const int wave = tid >> 6;
    const int lane = tid & 63;

    // issue one 16 KB stage: 4 wave-level global_load_lds_dwordx4 per wave
    auto issue = [&](int s, int buf) {
#pragma unroll
        for (int p = 0; p < 4; p++) {
            const float4* g = p4 + (base0 + s * STAGE_F4 + p * 256 + tid);
            // LDS dest: wave-uniform base + lane*16
            void* lp = (void*)&sbuf[buf][p * 256 + wave * 64];
            __builtin_amdgcn_global_load_lds(
                (const __attribute__((address_space(1))) void*)g,
                (__attribute__((address_space(3))) void*)lp,
                16, 0, 0);
        }
    };

    unsigned mcur[4], mnxt[4];

    issue(0, 0);
#pragma unroll
    for (int p = 0; p < 4; p++) mcur[p] = packed[base0 + p * 256 + tid];
    __syncthreads();   // drains vmcnt(0): stage 0 + mcur ready

    float ce = 0.f, inter = 0.f, gnd = 0.f, po = 0.f;

    for (int s = 0; s < NSTAGES; s++) {
        const int cb = s & 1;
        if (s + 1 < NSTAGES) {
            issue(s + 1, cb ^ 1);
            const int nbase = base0 + (s + 1) * STAGE_F4;
#pragma unroll
            for (int p = 0; p < 4; p++) mnxt[p] = packed[nbase + p * 256 + tid];
        }

#pragma unroll
        for (int p = 0; p < 4; p++) {
            const float4 v = sbuf[cb][p * 256 + tid];
            const unsigned m = mcur[p];
#define COMP(pv, sh)                                                     \
            {                                                            \
                const int c0 = (int)((m >> (sh))     & 7u) == n;         \
                const int c1 = (int)((m >> ((sh)+3)) & 7u) == n;         \
                const float lg = __log2f((pv) + EPSF);                   \
                ce += (float)(c0 + c1) * lg;                             \
                const int mb = b ? c1 : c0;                              \
                inter += mb ? (pv) : 0.f;                                \
                gnd   += (float)mb;                                      \
                po    += (pv);                                           \
            }
            COMP(v.x, 0) COMP(v.y, 6) COMP(v.z, 12) COMP(v.w, 18)
#undef COMP
        }

#pragma unroll
        for (int p = 0; p < 4; p++) mcur[p] = mnxt[p];
        __syncthreads();  // next stage complete; current buffer free for reuse
    }

    // ---- block reduction: 64-lane shuffle -> LDS -> 4 atomics ----
    float v4[4] = {ce, inter, gnd, po};
#pragma unroll
    for (int i = 0; i < 4; i++) {
#pragma unroll
        for (int off = 32; off > 0; off >>= 1)
            v4[i] += __shfl_down(v4[i], off, 64);
        if (lane == 0) red[wave][i] = v4[i];
    }
    __syncthreads();
    if (tid < 4) {
        const float s = red[0][tid] + red[1][tid] + red[2][tid] + red[3][tid];
        const int slot = (tid == 0) ? 0
                       : (tid == 1) ? (1 + plane)
                       : (tid == 2) ? (17 + plane)
                       : (33 + plane);
        atomicAdd(&ws[slot], s);
    }

    // ---- last-block finalize ----
    __threadfence();
    __syncthreads();
    if (tid == 0) {
        const unsigned prev = atomicAdd((unsigned int*)(ws + NACC), 1u);
        if (prev == (unsigned)(gridDim.x - 1)) {
            float acc[NACC];
#pragma unroll
            for (int i = 0; i < NACC; i++) acc[i] = atomicAdd(&ws[i], 0.0f); // coherent read
            float dice = 0.f;
#pragma unroll
            for (int k = 0; k < 16; k++)
                dice += 1.0f - (2.0f * acc[1 + k] + SMOOTHF) / (acc[17 + k] + acc[33 + k] + SMOOTHF);
            out[0] = -(acc[0] * LN2F) / (4.0f * (float)S_VOX) + dice * (1.0f / 16.0f);
        }
    }
}

extern "C" void kernel_launch(void* const* d_in, const int* in_sizes, int n_in,
                              void* d_out, int out_size, void* d_ws, size_t ws_size,
                              hipStream_t stream) {
    const float* pred = (const float*)d_in[0];
    const int*   tgt  = (const int*)d_in[1];
    float*        ws     = (float*)d_ws;                 // [0..49]
    unsigned int* packed = (unsigned int*)(ws + 64);     // QV u32 = 2 MB scratch
    float* out = (float*)d_out;

    pack_targets<<<QV / 1024, 256, 0, stream>>>(tgt, packed, ws);
    dice_main<<<NBLK, 256, 0, stream>>>(pred, packed, ws, out);
}